// Round 2
// baseline (472.822 us; speedup 1.0000x reference)
//
#include <hip/hip_runtime.h>

// NeuralODE: x_{s+1} = x + (tanh(tanh(x W1 + b1) W2 + b2) W3 + b3) * dt_scale * DT
// BATCH=4096, STATE=64, HIDDEN=256, steps=200. Output [4096, 201, 64] fp32.
//
// R2: 1024 threads / 16 waves per block, 256 blocks (1/CU, 4 waves/SIMD).
// Each wave owns 16 of the 256 hidden cols for L1/L2 (W1/W2 B-frags in regs).
// W3 B-frags staged in LDS. Activations in LDS bf16 with XOR chunk swizzle
// (chunk ^= row&7 at 16B granularity) -> even bank spread for b128 reads and
// conflict-free-ish b16 writes. fp32 x state ping-pongs in LDS (pitch 65).
// Trajectory written by the 12 non-L3 waves during the L3 phase.

#define STATE_DIM 64
#define HIDDEN    256
#define TILE_M    16
#define NBLK      256

typedef short v8s __attribute__((ext_vector_type(8)));
typedef float v4f __attribute__((ext_vector_type(4)));

__device__ __forceinline__ unsigned short f2bf(float f) {
    // round-half-up to bf16 (2 VALU ops; bias negligible vs RNE)
    return (unsigned short)((__float_as_uint(f) + 0x8000u) >> 16);
}

__device__ __forceinline__ float fast_tanh(float x) {
    float e = __builtin_amdgcn_exp2f(x * 2.8853900817779268f);  // exp(2x)
    return 1.0f - 2.0f * __builtin_amdgcn_rcpf(e + 1.0f);
}

// ---- prep: fp32 weights -> bf16, transposed to [N][K] ----
__global__ void prep_weights(const float* __restrict__ W1,
                             const float* __restrict__ W2,
                             const float* __restrict__ W3,
                             short* __restrict__ W1t,   // [256][64]
                             short* __restrict__ W2t,   // [256][256]
                             short* __restrict__ W3t) { // [64][256]
    int u = blockIdx.x * 256 + threadIdx.x;
    if (u < 65536) {                       // W2t[n][k] = W2[k][n]
        int n = u >> 8, k = u & 255;
        W2t[u] = (short)f2bf(W2[k * 256 + n]);
    }
    int v = u - 65536;
    if (v >= 0 && v < 16384) {             // W1t[n][k] = W1[k][n]
        int n = v >> 6, k = v & 63;
        W1t[v] = (short)f2bf(W1[k * 256 + n]);
    }
    int t = u - (65536 + 16384);
    if (t >= 0 && t < 16384) {             // W3t[n][k] = W3[k][n]
        int n = t >> 8, k = t & 255;
        W3t[t] = (short)f2bf(W3[k * 64 + n]);
    }
}

__global__ __launch_bounds__(1024)
void ode_kernel(const float* __restrict__ x0,
                const float* __restrict__ b1,
                const float* __restrict__ b2,
                const float* __restrict__ b3,
                const float* __restrict__ dt_scale,
                const int*   __restrict__ stepsp,
                const short* __restrict__ W1t,
                const short* __restrict__ W2t,
                const short* __restrict__ W3t,
                float* __restrict__ out) {
    __shared__ short h1b[TILE_M * HIDDEN];      // 8 KB, swizzled
    __shared__ short h2b[TILE_M * HIDDEN];      // 8 KB, swizzled
    __shared__ short xb [TILE_M * STATE_DIM];   // 2 KB, swizzled
    __shared__ short w3s[STATE_DIM * HIDDEN];   // 32 KB, swizzled B-frags
    __shared__ float xs [2][TILE_M * 65];       // 8.3 KB, ping-pong fp32 state

    const int tid  = threadIdx.x;
    const int w    = tid >> 6;        // wave 0..15
    const int lane = tid & 63;
    const int ln   = lane & 15;
    const int q    = lane >> 4;
    const int blk  = blockIdx.x;
    const int nsteps = *stepsp;
    const float scale = dt_scale[0] * 0.01f;
    const int n0 = 16 * w;            // this wave's L1/L2 output cols

    // ---- weight B-fragments in registers ----
    v8s w1f[2], w2f[8];
    #pragma unroll
    for (int ks = 0; ks < 2; ks++)
        w1f[ks] = *(const v8s*)(W1t + (n0 + ln) * 64 + 32 * ks + 8 * q);
    #pragma unroll
    for (int ks = 0; ks < 8; ks++)
        w2f[ks] = *(const v8s*)(W2t + (n0 + ln) * 256 + 32 * ks + 8 * q);
    const float b1r = b1[n0 + ln];
    const float b2r = b2[n0 + ln];
    const float b3r = b3[16 * (w & 3) + ln];

    // ---- stage W3 into LDS (swizzled) ----
    #pragma unroll
    for (int c2 = 0; c2 < 2; c2++) {
        int u = c2 * 1024 + tid;
        int r = u >> 5, cb = u & 31;
        v8s v = *(const v8s*)(W3t + r * 256 + cb * 8);
        *(v8s*)(w3s + r * 256 + ((cb ^ (r & 7)) << 3)) = v;
    }
    // ---- stage x0: wave w handles batch row w ----
    {
        float v = x0[(size_t)(blk * TILE_M + w) * STATE_DIM + lane];
        xs[0][w * 65 + lane] = v;
        xb[w * 64 + (((lane >> 3) ^ (w & 7)) << 3) + (lane & 7)] = (short)f2bf(v);
    }
    __syncthreads();

    // ---- hoisted LDS addresses (short indices, loop-invariant) ----
    int hrd[8], hwr[4], xrd[2], w3rd[8], xwr[4], xsi[4];
    #pragma unroll
    for (int ks = 0; ks < 8; ks++)
        hrd[ks] = ln * 256 + (((4 * ks + q) ^ (ln & 7)) << 3);
    #pragma unroll
    for (int ks = 0; ks < 2; ks++)
        xrd[ks] = ln * 64 + (((4 * ks + q) ^ (ln & 7)) << 3);
    #pragma unroll
    for (int i = 0; i < 4; i++) {
        int r = 4 * q + i, c = n0 + ln;
        hwr[i] = r * 256 + (((c >> 3) ^ (r & 7)) << 3) + (c & 7);
    }
    {
        int r3 = 16 * (w & 3) + ln;
        #pragma unroll
        for (int ks = 0; ks < 8; ks++)
            w3rd[ks] = r3 * 256 + (((4 * ks + q) ^ (r3 & 7)) << 3);
        #pragma unroll
        for (int i = 0; i < 4; i++) {
            int r = 4 * q + i, c = 16 * (w & 3) + ln;
            xwr[i] = r * 64 + (((c >> 3) ^ (r & 7)) << 3) + (c & 7);
            xsi[i] = r * 65 + c;
        }
    }

    // ---- trajectory-write assignments (waves 4..15) ----
    const size_t orow = (size_t)(nsteps + 1) * STATE_DIM;
    float* tp1 = out;
    float* tp2 = out;
    int xsr1 = 0, xsr2 = 0;
    if (w >= 4) {
        tp1  = out + (size_t)(blk * TILE_M + (w - 4)) * orow + lane;
        xsr1 = (w - 4) * 65 + lane;
    }
    if (w >= 4 && w < 8) {
        tp2  = out + (size_t)(blk * TILE_M + (w + 8)) * orow + lane;
        xsr2 = (w + 8) * 65 + lane;
    }

    for (int s = 0; s < nsteps; s++) {
        const int cur = s & 1, nxt = cur ^ 1;

        // ---- L1: h1 = tanh(x @ W1 + b1) ----
        v4f acc = {0.f, 0.f, 0.f, 0.f};
        #pragma unroll
        for (int ks = 0; ks < 2; ks++) {
            v8s a = *(const v8s*)(xb + xrd[ks]);
            acc = __builtin_amdgcn_mfma_f32_16x16x32_bf16(a, w1f[ks], acc, 0, 0, 0);
        }
        #pragma unroll
        for (int i = 0; i < 4; i++)
            h1b[hwr[i]] = (short)f2bf(fast_tanh(acc[i] + b1r));
        __syncthreads();

        // ---- L2: h2 = tanh(h1 @ W2 + b2) ----
        acc = (v4f){0.f, 0.f, 0.f, 0.f};
        #pragma unroll
        for (int ks = 0; ks < 8; ks++) {
            v8s a = *(const v8s*)(h1b + hrd[ks]);
            acc = __builtin_amdgcn_mfma_f32_16x16x32_bf16(a, w2f[ks], acc, 0, 0, 0);
        }
        #pragma unroll
        for (int i = 0; i < 4; i++)
            h2b[hwr[i]] = (short)f2bf(fast_tanh(acc[i] + b2r));
        __syncthreads();

        // ---- phase 3: L3 + Euler (waves 0-3) | trajectory write (waves 4-15) ----
        if (w < 4) {
            v4f a3 = {0.f, 0.f, 0.f, 0.f};
            #pragma unroll
            for (int ks = 0; ks < 8; ks++) {
                v8s a = *(const v8s*)(h2b + hrd[ks]);
                v8s b = *(const v8s*)(w3s + w3rd[ks]);
                a3 = __builtin_amdgcn_mfma_f32_16x16x32_bf16(a, b, a3, 0, 0, 0);
            }
            #pragma unroll
            for (int i = 0; i < 4; i++) {
                float xo = xs[cur][xsi[i]];
                float xn = xo + (a3[i] + b3r) * scale;
                xs[nxt][xsi[i]] = xn;
                xb[xwr[i]] = (short)f2bf(xn);
            }
        } else {
            *tp1 = xs[cur][xsr1];
            tp1 += STATE_DIM;
            if (w < 8) {
                *tp2 = xs[cur][xsr2];
                tp2 += STATE_DIM;
            }
        }
        __syncthreads();
    }

    // ---- final sample s = nsteps: wave w writes batch row w ----
    {
        float v = xs[nsteps & 1][w * 65 + lane];
        out[(size_t)(blk * TILE_M + w) * orow + (size_t)nsteps * STATE_DIM + lane] = v;
    }
}

extern "C" void kernel_launch(void* const* d_in, const int* in_sizes, int n_in,
                              void* d_out, int out_size, void* d_ws, size_t ws_size,
                              hipStream_t stream) {
    const float* x0 = (const float*)d_in[0];
    const float* W1 = (const float*)d_in[1];
    const float* b1 = (const float*)d_in[2];
    const float* W2 = (const float*)d_in[3];
    const float* b2 = (const float*)d_in[4];
    const float* W3 = (const float*)d_in[5];
    const float* b3 = (const float*)d_in[6];
    const float* dt = (const float*)d_in[7];
    const int* steps = (const int*)d_in[8];

    short* W1t = (short*)d_ws;            // 16384 bf16
    short* W2t = W1t + 64 * 256;          // 65536 bf16
    short* W3t = W2t + 256 * 256;         // 16384 bf16

    prep_weights<<<384, 256, 0, stream>>>(W1, W2, W3, W1t, W2t, W3t);
    ode_kernel<<<NBLK, 1024, 0, stream>>>(x0, b1, b2, b3, dt, steps,
                                          W1t, W2t, W3t, (float*)d_out);
}

// Round 3
// 448.548 us; speedup vs baseline: 1.0541x; 1.0541x over previous
//
#include <hip/hip_runtime.h>

// NeuralODE: x_{s+1} = x + (tanh(tanh(x W1 + b1) W2 + b2) W3 + b3) * dt_scale * DT
// BATCH=4096, STATE=64, HIDDEN=256, steps=200. Output [4096, 201, 64] fp32.
//
// R3 = refined R1: 8 waves (512 thr) / block, 256 blocks (1/CU), TILE_M=16.
// Each wave owns 32 of 256 hidden cols (W1/W2 B-frags in regs, dual acc ILP).
// W3 frags in regs of waves 0-3. Trajectory write overlapped into L3 phase
// (waves 4-7). fp32 x ping-pongs in LDS at pitch 68 (2-way = free). All LDS
// addresses hoisted; L2 A-frags preloaded as a batch for scheduling.

#define STATE_DIM 64
#define HIDDEN    256
#define TILE_M    16
#define NBLK      256
#define XPITCH    72      // bf16 x pitch (shorts)
#define HPITCH    264     // bf16 h pitch (shorts)
#define XSP       68      // fp32 xs pitch (floats): 2-way bank alias only

typedef short v8s __attribute__((ext_vector_type(8)));
typedef float v4f __attribute__((ext_vector_type(4)));

__device__ __forceinline__ unsigned short f2bf(float f) {
    return (unsigned short)((__float_as_uint(f) + 0x8000u) >> 16);  // round-half-up
}

__device__ __forceinline__ float fast_tanh(float x) {
    float e = __builtin_amdgcn_exp2f(x * 2.8853900817779268f);  // exp(2x)
    return 1.0f - 2.0f * __builtin_amdgcn_rcpf(e + 1.0f);
}

// ---- prep: fp32 weights -> bf16, transposed to [N][K] ----
__global__ void prep_weights(const float* __restrict__ W1,
                             const float* __restrict__ W2,
                             const float* __restrict__ W3,
                             short* __restrict__ W1t,   // [256][64]
                             short* __restrict__ W2t,   // [256][256]
                             short* __restrict__ W3t) { // [64][256]
    int u = blockIdx.x * 256 + threadIdx.x;
    if (u < 65536) {                       // W2t[n][k] = W2[k][n]
        int n = u >> 8, k = u & 255;
        W2t[u] = (short)f2bf(W2[k * 256 + n]);
    }
    int v = u - 65536;
    if (v >= 0 && v < 16384) {             // W1t[n][k] = W1[k][n]
        int n = v >> 6, k = v & 63;
        W1t[v] = (short)f2bf(W1[k * 256 + n]);
    }
    int t = u - (65536 + 16384);
    if (t >= 0 && t < 16384) {             // W3t[n][k] = W3[k][n]
        int n = t >> 8, k = t & 255;
        W3t[t] = (short)f2bf(W3[k * 64 + n]);
    }
}

__global__ __launch_bounds__(512, 2)
void ode_kernel(const float* __restrict__ x0,
                const float* __restrict__ b1,
                const float* __restrict__ b2,
                const float* __restrict__ b3,
                const float* __restrict__ dt_scale,
                const int*   __restrict__ stepsp,
                const short* __restrict__ W1t,
                const short* __restrict__ W2t,
                const short* __restrict__ W3t,
                float* __restrict__ out) {
    __shared__ short xb [TILE_M * XPITCH];    // bf16 x (A source)
    __shared__ short h1b[TILE_M * HPITCH];
    __shared__ short h2b[TILE_M * HPITCH];
    __shared__ float xs [2][TILE_M * XSP];    // fp32 x ping-pong

    const int tid  = threadIdx.x;
    const int w    = tid >> 6;        // wave 0..7
    const int lane = tid & 63;
    const int ln   = lane & 15;
    const int q    = lane >> 4;
    const int blk  = blockIdx.x;
    const int nsteps = *stepsp;
    const float scale = dt_scale[0] * 0.01f;
    const int n0 = 32 * w;            // this wave's 32 L1/L2 output cols

    // ---- weight B-fragments in registers ----
    v8s w1f[2][2], w2f[2][8], w3f[8];
    #pragma unroll
    for (int t = 0; t < 2; t++)
        #pragma unroll
        for (int ks = 0; ks < 2; ks++)
            w1f[t][ks] = *(const v8s*)(W1t + (n0 + 16 * t + ln) * 64 + 32 * ks + 8 * q);
    #pragma unroll
    for (int t = 0; t < 2; t++)
        #pragma unroll
        for (int ks = 0; ks < 8; ks++)
            w2f[t][ks] = *(const v8s*)(W2t + (n0 + 16 * t + ln) * 256 + 32 * ks + 8 * q);
    if (w < 4) {
        #pragma unroll
        for (int ks = 0; ks < 8; ks++)
            w3f[ks] = *(const v8s*)(W3t + (16 * w + ln) * 256 + 32 * ks + 8 * q);
    }
    float b1r[2], b2r[2], b3r = 0.0f;
    #pragma unroll
    for (int t = 0; t < 2; t++) {
        b1r[t] = b1[n0 + 16 * t + ln];
        b2r[t] = b2[n0 + 16 * t + ln];
    }
    if (w < 4) b3r = b3[16 * w + ln];

    // ---- init x from x0 ----
    {
        int r = tid >> 5, c = (tid & 31) * 2;
        const float2 v = *(const float2*)(x0 + (size_t)(blk * TILE_M + r) * STATE_DIM + c);
        xs[0][r * XSP + c]     = v.x;
        xs[0][r * XSP + c + 1] = v.y;
        xb[r * XPITCH + c]     = (short)f2bf(v.x);
        xb[r * XPITCH + c + 1] = (short)f2bf(v.y);
    }
    __syncthreads();

    // ---- hoisted LDS element indices ----
    int xrd[2], hrd[8], hw0, xsU[4], xbU[4];
    #pragma unroll
    for (int ks = 0; ks < 2; ks++) xrd[ks] = ln * XPITCH + 32 * ks + 8 * q;
    #pragma unroll
    for (int ks = 0; ks < 8; ks++) hrd[ks] = ln * HPITCH + 32 * ks + 8 * q;
    hw0 = (4 * q) * HPITCH + n0 + ln;           // h write base (row 4q, tile t via +16, row i via +i*HPITCH)
    {
        int col = 16 * (w & 3) + ln;
        #pragma unroll
        for (int i = 0; i < 4; i++) {
            xsU[i] = (4 * q + i) * XSP + col;
            xbU[i] = (4 * q + i) * XPITCH + col;
        }
    }

    // ---- trajectory pointers (waves 4..7 write rows 4*(w-4)..+3) ----
    const size_t orow = (size_t)(nsteps + 1) * STATE_DIM;
    float* tp[4];
    int trd[4];
    {
        int r0 = 4 * (w - 4);
        #pragma unroll
        for (int j = 0; j < 4; j++) {
            int r = (w >= 4) ? (r0 + j) : 0;
            tp[j]  = out + (size_t)(blk * TILE_M + r) * orow + lane;
            trd[j] = r * XSP + lane;
        }
    }

    for (int s = 0; s < nsteps; s++) {
        const int cur = s & 1, nxt = cur ^ 1;

        // ---- L1: h1 = tanh(x @ W1 + b1), K=64, dual 16-col tiles ----
        v8s xa0 = *(const v8s*)(xb + xrd[0]);
        v8s xa1 = *(const v8s*)(xb + xrd[1]);
        v4f acc0 = {0.f, 0.f, 0.f, 0.f}, acc1 = {0.f, 0.f, 0.f, 0.f};
        acc0 = __builtin_amdgcn_mfma_f32_16x16x32_bf16(xa0, w1f[0][0], acc0, 0, 0, 0);
        acc1 = __builtin_amdgcn_mfma_f32_16x16x32_bf16(xa0, w1f[1][0], acc1, 0, 0, 0);
        acc0 = __builtin_amdgcn_mfma_f32_16x16x32_bf16(xa1, w1f[0][1], acc0, 0, 0, 0);
        acc1 = __builtin_amdgcn_mfma_f32_16x16x32_bf16(xa1, w1f[1][1], acc1, 0, 0, 0);
        #pragma unroll
        for (int i = 0; i < 4; i++) {
            h1b[hw0 + i * HPITCH]      = (short)f2bf(fast_tanh(acc0[i] + b1r[0]));
            h1b[hw0 + i * HPITCH + 16] = (short)f2bf(fast_tanh(acc1[i] + b1r[1]));
        }
        __syncthreads();

        // ---- L2: h2 = tanh(h1 @ W2 + b2), K=256 ----
        v8s a[8];
        #pragma unroll
        for (int ks = 0; ks < 8; ks++) a[ks] = *(const v8s*)(h1b + hrd[ks]);
        acc0 = (v4f){0.f, 0.f, 0.f, 0.f};
        acc1 = (v4f){0.f, 0.f, 0.f, 0.f};
        #pragma unroll
        for (int ks = 0; ks < 8; ks++) {
            acc0 = __builtin_amdgcn_mfma_f32_16x16x32_bf16(a[ks], w2f[0][ks], acc0, 0, 0, 0);
            acc1 = __builtin_amdgcn_mfma_f32_16x16x32_bf16(a[ks], w2f[1][ks], acc1, 0, 0, 0);
        }
        #pragma unroll
        for (int i = 0; i < 4; i++) {
            h2b[hw0 + i * HPITCH]      = (short)f2bf(fast_tanh(acc0[i] + b2r[0]));
            h2b[hw0 + i * HPITCH + 16] = (short)f2bf(fast_tanh(acc1[i] + b2r[1]));
        }
        __syncthreads();

        // ---- phase 3: L3 + Euler (waves 0-3) | trajectory write (waves 4-7) ----
        if (w < 4) {
            v8s c[8];
            #pragma unroll
            for (int ks = 0; ks < 8; ks++) c[ks] = *(const v8s*)(h2b + hrd[ks]);
            v4f a3 = {0.f, 0.f, 0.f, 0.f};
            #pragma unroll
            for (int ks = 0; ks < 8; ks++)
                a3 = __builtin_amdgcn_mfma_f32_16x16x32_bf16(c[ks], w3f[ks], a3, 0, 0, 0);
            #pragma unroll
            for (int i = 0; i < 4; i++) {
                float xn = xs[cur][xsU[i]] + (a3[i] + b3r) * scale;
                xs[nxt][xsU[i]] = xn;
                xb[xbU[i]] = (short)f2bf(xn);
            }
        } else {
            #pragma unroll
            for (int j = 0; j < 4; j++) {
                *tp[j] = xs[cur][trd[j]];
                tp[j] += STATE_DIM;
            }
        }
        __syncthreads();
    }

    // ---- final sample s = nsteps: 8 waves × 2 rows ----
    {
        const float* xsf = xs[nsteps & 1];
        #pragma unroll
        for (int j = 0; j < 2; j++) {
            int r = 2 * w + j;
            out[(size_t)(blk * TILE_M + r) * orow + (size_t)nsteps * STATE_DIM + lane] =
                xsf[r * XSP + lane];
        }
    }
}

extern "C" void kernel_launch(void* const* d_in, const int* in_sizes, int n_in,
                              void* d_out, int out_size, void* d_ws, size_t ws_size,
                              hipStream_t stream) {
    const float* x0 = (const float*)d_in[0];
    const float* W1 = (const float*)d_in[1];
    const float* b1 = (const float*)d_in[2];
    const float* W2 = (const float*)d_in[3];
    const float* b2 = (const float*)d_in[4];
    const float* W3 = (const float*)d_in[5];
    const float* b3 = (const float*)d_in[6];
    const float* dt = (const float*)d_in[7];
    const int* steps = (const int*)d_in[8];

    short* W1t = (short*)d_ws;            // 16384 bf16
    short* W2t = W1t + 64 * 256;          // 65536 bf16
    short* W3t = W2t + 256 * 256;         // 16384 bf16

    prep_weights<<<384, 256, 0, stream>>>(W1, W2, W3, W1t, W2t, W3t);
    ode_kernel<<<NBLK, 512, 0, stream>>>(x0, b1, b2, b3, dt, steps,
                                         W1t, W2t, W3t, (float*)d_out);
}

// Round 4
// 430.224 us; speedup vs baseline: 1.0990x; 1.0426x over previous
//
#include <hip/hip_runtime.h>

// NeuralODE: x_{s+1} = x + (tanh(tanh(x W1 + b1) W2 + b2) W3 + b3) * dt_scale * DT
// BATCH=4096, STATE=64, HIDDEN=256, steps=200. Output [4096, 201, 64] fp32.
//
// R4: operand-swapped MFMA (weights=A, activations=B). C-layout gives each
// lane 4 consecutive output features -> b64 LDS epilogue writes, bias folded
// into acc init, x state in registers of waves 0-3 (no fp32 LDS state),
// trajectory stored as dwordx4 straight from registers. 8 waves / 256 blocks.

#define STATE_DIM 64
#define HIDDEN    256
#define TILE_M    16
#define NBLK      256
#define XPITCH    68      // bf16 x pitch (shorts): mult of 4, non-pow2 banking
#define HPITCH    260     // bf16 h pitch (shorts): quads land on distinct banks

typedef short v8s __attribute__((ext_vector_type(8)));
typedef float v4f __attribute__((ext_vector_type(4)));

__device__ __forceinline__ unsigned short f2bf(float f) {
    return (unsigned short)((__float_as_uint(f) + 0x8000u) >> 16);  // round-half-up
}
__device__ __forceinline__ unsigned pk2bf(float a, float b) {
    return ((__float_as_uint(a) + 0x8000u) >> 16) |
           ((__float_as_uint(b) + 0x8000u) & 0xffff0000u);
}
__device__ __forceinline__ float fast_tanh(float x) {
    float e = __builtin_amdgcn_exp2f(x * 2.8853900817779268f);  // exp(2x)
    return 1.0f - 2.0f * __builtin_amdgcn_rcpf(e + 1.0f);
}

// ---- prep: fp32 weights -> bf16, transposed to [N][K] ----
__global__ void prep_weights(const float* __restrict__ W1,
                             const float* __restrict__ W2,
                             const float* __restrict__ W3,
                             short* __restrict__ W1t,   // [256][64]
                             short* __restrict__ W2t,   // [256][256]
                             short* __restrict__ W3t) { // [64][256]
    int u = blockIdx.x * 256 + threadIdx.x;
    if (u < 65536) {                       // W2t[n][k] = W2[k][n]
        int n = u >> 8, k = u & 255;
        W2t[u] = (short)f2bf(W2[k * 256 + n]);
    }
    int v = u - 65536;
    if (v >= 0 && v < 16384) {             // W1t[n][k] = W1[k][n]
        int n = v >> 6, k = v & 63;
        W1t[v] = (short)f2bf(W1[k * 256 + n]);
    }
    int t = u - (65536 + 16384);
    if (t >= 0 && t < 16384) {             // W3t[n][k] = W3[k][n]
        int n = t >> 8, k = t & 255;
        W3t[t] = (short)f2bf(W3[k * 64 + n]);
    }
}

__global__ __launch_bounds__(512, 2)
void ode_kernel(const float* __restrict__ x0,
                const float* __restrict__ b1,
                const float* __restrict__ b2,
                const float* __restrict__ b3,
                const float* __restrict__ dt_scale,
                const int*   __restrict__ stepsp,
                const short* __restrict__ W1t,
                const short* __restrict__ W2t,
                const short* __restrict__ W3t,
                float* __restrict__ out) {
    __shared__ short xb [TILE_M * XPITCH];    // bf16 x, B-operand source
    __shared__ short h1b[TILE_M * HPITCH];
    __shared__ short h2b[TILE_M * HPITCH];

    const int tid  = threadIdx.x;
    const int w    = tid >> 6;        // wave 0..7
    const int lane = tid & 63;
    const int ln   = lane & 15;       // batch row (B col / C col)
    const int q    = lane >> 4;
    const int blk  = blockIdx.x;
    const int nsteps = *stepsp;
    const float scale = dt_scale[0] * 0.01f;
    const int n0 = 32 * w;            // this wave's 32 output features (L1/L2)

    // ---- weight A-fragments in registers (A[m=ln][k=32ks+8q+j]) ----
    v8s w1f[2][2], w2f[2][8], w3f[8];
    #pragma unroll
    for (int t = 0; t < 2; t++)
        #pragma unroll
        for (int ks = 0; ks < 2; ks++)
            w1f[t][ks] = *(const v8s*)(W1t + (n0 + 16 * t + ln) * 64 + 32 * ks + 8 * q);
    #pragma unroll
    for (int t = 0; t < 2; t++)
        #pragma unroll
        for (int ks = 0; ks < 8; ks++)
            w2f[t][ks] = *(const v8s*)(W2t + (n0 + 16 * t + ln) * 256 + 32 * ks + 8 * q);
    if (w < 4) {
        #pragma unroll
        for (int ks = 0; ks < 8; ks++)
            w3f[ks] = *(const v8s*)(W3t + (16 * w + ln) * 256 + 32 * ks + 8 * q);
    }
    // ---- biases as per-lane float4 (C rows = feats 4q+i) ----
    v4f b1v[2], b2v[2], b3v = {0.f, 0.f, 0.f, 0.f};
    #pragma unroll
    for (int t = 0; t < 2; t++) {
        b1v[t] = *(const v4f*)(b1 + n0 + 16 * t + 4 * q);
        b2v[t] = *(const v4f*)(b2 + n0 + 16 * t + 4 * q);
    }
    if (w < 4) b3v = *(const v4f*)(b3 + 16 * w + 4 * q);

    // ---- x state in registers of waves 0-3: feats 16w+4q+i, batch ln ----
    v4f x = {0.f, 0.f, 0.f, 0.f};
    unsigned tbase = 0;
    const int xw0 = ln * XPITCH + 16 * w + 4 * q;
    if (w < 4) {
        x = *(const v4f*)(x0 + (size_t)(blk * TILE_M + ln) * STATE_DIM + 16 * w + 4 * q);
        uint2 p; p.x = pk2bf(x[0], x[1]); p.y = pk2bf(x[2], x[3]);
        *(uint2*)(xb + xw0) = p;
        tbase = (unsigned)(blk * TILE_M + ln) * (unsigned)((nsteps + 1) * STATE_DIM)
              + 16 * w + 4 * q;
        *(v4f*)(out + tbase) = x;          // trajectory sample 0
        tbase += STATE_DIM;
    }
    __syncthreads();

    // ---- hoisted LDS indices ----
    int xrd[2], hrd[8];
    #pragma unroll
    for (int ks = 0; ks < 2; ks++) xrd[ks] = ln * XPITCH + 32 * ks + 8 * q;
    #pragma unroll
    for (int ks = 0; ks < 8; ks++) hrd[ks] = ln * HPITCH + 32 * ks + 8 * q;
    const int hw0 = ln * HPITCH + n0 + 4 * q;   // + 16*t for tile t

    for (int s = 0; s < nsteps; s++) {
        // ---- L1: h1 = tanh(x @ W1 + b1)  (A=W1 frags, B=xb) ----
        v8s xa0 = *(const v8s*)(xb + xrd[0]);
        v8s xa1 = *(const v8s*)(xb + xrd[1]);
        v4f a0 = b1v[0], a1 = b1v[1];
        a0 = __builtin_amdgcn_mfma_f32_16x16x32_bf16(w1f[0][0], xa0, a0, 0, 0, 0);
        a1 = __builtin_amdgcn_mfma_f32_16x16x32_bf16(w1f[1][0], xa0, a1, 0, 0, 0);
        a0 = __builtin_amdgcn_mfma_f32_16x16x32_bf16(w1f[0][1], xa1, a0, 0, 0, 0);
        a1 = __builtin_amdgcn_mfma_f32_16x16x32_bf16(w1f[1][1], xa1, a1, 0, 0, 0);
        {
            uint2 p0, p1;
            p0.x = pk2bf(fast_tanh(a0[0]), fast_tanh(a0[1]));
            p0.y = pk2bf(fast_tanh(a0[2]), fast_tanh(a0[3]));
            p1.x = pk2bf(fast_tanh(a1[0]), fast_tanh(a1[1]));
            p1.y = pk2bf(fast_tanh(a1[2]), fast_tanh(a1[3]));
            *(uint2*)(h1b + hw0)      = p0;
            *(uint2*)(h1b + hw0 + 16) = p1;
        }
        __syncthreads();

        // ---- L2: h2 = tanh(h1 @ W2 + b2) ----
        v8s ha[8];
        #pragma unroll
        for (int ks = 0; ks < 8; ks++) ha[ks] = *(const v8s*)(h1b + hrd[ks]);
        a0 = b2v[0]; a1 = b2v[1];
        #pragma unroll
        for (int ks = 0; ks < 8; ks++) {
            a0 = __builtin_amdgcn_mfma_f32_16x16x32_bf16(w2f[0][ks], ha[ks], a0, 0, 0, 0);
            a1 = __builtin_amdgcn_mfma_f32_16x16x32_bf16(w2f[1][ks], ha[ks], a1, 0, 0, 0);
        }
        {
            uint2 p0, p1;
            p0.x = pk2bf(fast_tanh(a0[0]), fast_tanh(a0[1]));
            p0.y = pk2bf(fast_tanh(a0[2]), fast_tanh(a0[3]));
            p1.x = pk2bf(fast_tanh(a1[0]), fast_tanh(a1[1]));
            p1.y = pk2bf(fast_tanh(a1[2]), fast_tanh(a1[3]));
            *(uint2*)(h2b + hw0)      = p0;
            *(uint2*)(h2b + hw0 + 16) = p1;
        }
        __syncthreads();

        // ---- L3 + Euler + trajectory store (waves 0-3; 4-7 idle) ----
        if (w < 4) {
            v8s hc[8];
            #pragma unroll
            for (int ks = 0; ks < 8; ks++) hc[ks] = *(const v8s*)(h2b + hrd[ks]);
            v4f a3 = b3v;
            #pragma unroll
            for (int ks = 0; ks < 8; ks++)
                a3 = __builtin_amdgcn_mfma_f32_16x16x32_bf16(w3f[ks], hc[ks], a3, 0, 0, 0);
            #pragma unroll
            for (int i = 0; i < 4; i++)
                x[i] = fmaf(a3[i], scale, x[i]);
            uint2 p; p.x = pk2bf(x[0], x[1]); p.y = pk2bf(x[2], x[3]);
            *(uint2*)(xb + xw0) = p;
            *(v4f*)(out + tbase) = x;      // trajectory sample s+1
            tbase += STATE_DIM;
        }
        __syncthreads();
    }
}

extern "C" void kernel_launch(void* const* d_in, const int* in_sizes, int n_in,
                              void* d_out, int out_size, void* d_ws, size_t ws_size,
                              hipStream_t stream) {
    const float* x0 = (const float*)d_in[0];
    const float* W1 = (const float*)d_in[1];
    const float* b1 = (const float*)d_in[2];
    const float* W2 = (const float*)d_in[3];
    const float* b2 = (const float*)d_in[4];
    const float* W3 = (const float*)d_in[5];
    const float* b3 = (const float*)d_in[6];
    const float* dt = (const float*)d_in[7];
    const int* steps = (const int*)d_in[8];

    short* W1t = (short*)d_ws;            // 16384 bf16
    short* W2t = W1t + 64 * 256;          // 65536 bf16
    short* W3t = W2t + 256 * 256;         // 16384 bf16

    prep_weights<<<384, 256, 0, stream>>>(W1, W2, W3, W1t, W2t, W3t);
    ode_kernel<<<NBLK, 512, 0, stream>>>(x0, b1, b2, b3, dt, steps,
                                         W1t, W2t, W3t, (float*)d_out);
}